// Round 5
// baseline (612.142 us; speedup 1.0000x reference)
//
#include <hip/hip_runtime.h>
#include <hip/hip_bf16.h>

#define NB 2048
#define NF 6144
#define ND 768
#define BK 32
#define NT (NF / BK)  // 192 K-steps per layer

typedef __attribute__((ext_vector_type(4))) __bf16 bf16x4;
typedef __attribute__((ext_vector_type(8))) __bf16 bf16x8;
typedef __attribute__((ext_vector_type(4))) float f32x4;

// LDS tile: 128 rows x 32 bf16 (64 B rows). 16B-block swizzle (2-bit):
//   blk = (k>>3) ^ (row&3) ^ ((row>>2)&3)
// Hand-verified bank patterns: fragment ds_read_b128 (16 rows/quarter-wave,
// 4 k-blocks) uniform over 32 banks (8-phase floor); A ds_write_b128 uniform;
// B ds_write_b64 2-way (free). Row+64 leaves blk invariant (64>>2 = 16 == 0 mod 4).
__device__ __forceinline__ char* lds_addr(char* base, int row, int k) {
  const int blk = ((k >> 3) ^ (row & 3) ^ ((row >> 2) & 3)) & 3;
  return base + row * 64 + (blk << 4) + ((k & 7) << 1);
}

// Non-draining barrier: drain LDS ops only; global loads stay in flight
// (__syncthreads would emit vmcnt(0) and serialize the pipeline).
#define BAR()                                              \
  do {                                                     \
    asm volatile("s_waitcnt lgkmcnt(0)" ::: "memory");     \
    __builtin_amdgcn_sched_barrier(0);                     \
    __builtin_amdgcn_s_barrier();                          \
    __builtin_amdgcn_sched_barrier(0);                     \
  } while (0)

// out[b,d] = sum_l bias[l,d]  (also clears the 0xAA poison deterministically)
__global__ __launch_bounds__(256) void bias_init_kernel(
    const float* __restrict__ bias, const int* __restrict__ lidx,
    float* __restrict__ out) {
  int n = lidx[0] + 1;
  int i = blockIdx.x * 256 + threadIdx.x;
  if (i >= NB * ND) return;
  int d = i % ND;
  float s = 0.f;
  for (int l = 0; l < n; ++l) s += bias[l * ND + d];
  out[i] = s;
}

__global__ __launch_bounds__(256, 3) void gemm_kernel(
    const float* __restrict__ acts, const float* __restrict__ W,
    const int* __restrict__ lidx, float* __restrict__ out, int nwg) {
  // XCD-aware swizzle (bijective: nwg = 96*L, 96%8==0). Consecutive swz share
  // the same W panel (x fastest) -> panel stays in one XCD's L2.
  const int chunk = nwg >> 3;
  const int swz = (blockIdx.x & 7) * chunk + (blockIdx.x >> 3);
  const int bx = swz & 15;          // M tile (16)
  const int rem = swz >> 4;
  const int by = rem % 6;           // D tile (6)
  const int l = rem / 6;            // layer
  if (l > lidx[0]) return;          // uniform exit before any barrier

  const int brow = bx * 128;
  const int ncol = by * 128;

  // double-buffered: [buf][A(8KB) | B(8KB)]
  __shared__ char cbuf[2][16384];

  const int tid = threadIdx.x;
  const int lane = tid & 63;
  const int wid = tid >> 6;
  const int wrow = (wid >> 1) * 64;
  const int wcol = (wid & 1) * 64;

  f32x4 acc[4][4];
#pragma unroll
  for (int i = 0; i < 4; ++i)
#pragma unroll
    for (int j = 0; j < 4; ++j) acc[i][j] = (f32x4){0.f, 0.f, 0.f, 0.f};

  // A staging: thread -> (row = tid>>2 (+64 on pass 1), 8 consecutive k)
  const int s_arow = tid >> 2;        // 0..63
  const int s_ak = (tid & 3) * 8;     // 0,8,16,24
  // B staging: thread -> (4 consecutive d, 4 consecutive k)
  const int s_bd = (tid & 31) * 4;    // 0..124
  const int s_bk = (tid >> 5) * 4;    // 0..28

  const float* Aptr =
      acts + (size_t)l * NB * NF + (size_t)(brow + s_arow) * NF + s_ak;
  const float* Bptr =
      W + (size_t)l * NF * ND + (size_t)s_bk * ND + (ncol + s_bd);

  // single staging set: 32 VGPRs (acc64 + frags32 + staging32 + addr fits 168)
  float4 av[2][2];  // [pass][8 k]
  float4 bv[4];     // 4 k-rows x 4 d

  auto LOADS = [&](int kb) {
#pragma unroll
    for (int p = 0; p < 2; ++p) {
      av[p][0] = *(const float4*)(Aptr + (size_t)(64 * p) * NF + kb);
      av[p][1] = *(const float4*)(Aptr + (size_t)(64 * p) * NF + kb + 4);
    }
#pragma unroll
    for (int j = 0; j < 4; ++j)
      bv[j] = *(const float4*)(Bptr + (size_t)(kb + j) * ND);
  };

  auto STORE = [&](int buf) {
    char* cA_ = cbuf[buf];
    char* cB_ = cbuf[buf] + 8192;
#pragma unroll
    for (int p = 0; p < 2; ++p) {
      bf16x8 h;
      h[0] = (__bf16)av[p][0].x; h[1] = (__bf16)av[p][0].y;
      h[2] = (__bf16)av[p][0].z; h[3] = (__bf16)av[p][0].w;
      h[4] = (__bf16)av[p][1].x; h[5] = (__bf16)av[p][1].y;
      h[6] = (__bf16)av[p][1].z; h[7] = (__bf16)av[p][1].w;
      *(bf16x8*)lds_addr(cA_, s_arow + 64 * p, s_ak) = h;
    }
#pragma unroll
    for (int dd = 0; dd < 4; ++dd) {
      bf16x4 h;
      h[0] = (__bf16)bv[0][dd]; h[1] = (__bf16)bv[1][dd];
      h[2] = (__bf16)bv[2][dd]; h[3] = (__bf16)bv[3][dd];
      *(bf16x4*)lds_addr(cB_, s_bd + dd, s_bk) = h;  // b64, 8B-aligned
    }
  };

  auto KSTEP = [&](int buf) {
    char* cA_ = cbuf[buf];
    char* cB_ = cbuf[buf] + 8192;
    const int kk = (lane >> 4) * 8;
    bf16x8 aF[4], bF[4];
#pragma unroll
    for (int mi = 0; mi < 4; ++mi)
      aF[mi] = *(const bf16x8*)lds_addr(cA_, wrow + mi * 16 + (lane & 15), kk);
#pragma unroll
    for (int ni = 0; ni < 4; ++ni)
      bF[ni] = *(const bf16x8*)lds_addr(cB_, wcol + ni * 16 + (lane & 15), kk);
#pragma unroll
    for (int mi = 0; mi < 4; ++mi)
#pragma unroll
      for (int ni = 0; ni < 4; ++ni)
        acc[mi][ni] = __builtin_amdgcn_mfma_f32_16x16x32_bf16(
            aF[mi], bF[ni], acc[mi][ni], 0, 0, 0);
  };

  // ---- pipeline prologue ----
  LOADS(0);
  STORE(0);            // waits its own loads (startup only)
  LOADS(BK);           // slab 1 in flight

  // ---- main loop: one non-draining barrier per K-step, LDS double-buffer ---
  // BAR at top of iter t guarantees buf[t&1] fully written (STORE in t-1) and
  // buf[t^1] fully read (KSTEP in t-1) via lgkmcnt(0); vmcnt stays in flight.
  for (int t = 0; t < NT; ++t) {
    BAR();
    const int cur = t & 1;
    KSTEP(cur);
    if (t + 1 < NT) STORE(cur ^ 1);        // hw vmcnt wait via reg deps
    if (t + 2 < NT) LOADS((t + 2) * BK);   // consumed next iteration
  }

  // ---- epilogue: atomic accumulate (12 layer-blocks collide per output) ----
  // C/D layout (m89-verified): col = lane&15, row = (lane>>4)*4 + j
  const int orow = brow + wrow + ((lane >> 4) << 2);
  const int ocol = ncol + wcol + (lane & 15);
#pragma unroll
  for (int mi = 0; mi < 4; ++mi)
#pragma unroll
    for (int ni = 0; ni < 4; ++ni)
#pragma unroll
      for (int j = 0; j < 4; ++j)
        atomicAdd(out + (size_t)(orow + mi * 16 + j) * ND + (ocol + ni * 16),
                  acc[mi][ni][j]);
}

extern "C" void kernel_launch(void* const* d_in, const int* in_sizes, int n_in,
                              void* d_out, int out_size, void* d_ws, size_t ws_size,
                              hipStream_t stream) {
  const float* acts = (const float*)d_in[0];
  const float* W    = (const float*)d_in[1];
  const float* bias = (const float*)d_in[2];
  const int*   lidx = (const int*)d_in[3];
  float* out = (float*)d_out;

  const int L = in_sizes[0] / (NB * NF);  // 12
  const int nwg = (NB / 128) * (ND / 128) * L;  // 1152

  bias_init_kernel<<<dim3((NB * ND + 255) / 256), 256, 0, stream>>>(bias, lidx, out);
  gemm_kernel<<<dim3(nwg), 256, 0, stream>>>(acts, W, lidx, out, nwg);
}

// Round 6
// 575.856 us; speedup vs baseline: 1.0630x; 1.0630x over previous
//
#include <hip/hip_runtime.h>
#include <hip/hip_bf16.h>

#define NB 2048
#define NF 6144
#define ND 768
#define BM 256
#define BN 192
#define BK 64
#define SPLITK 2
#define KHALF (NF / SPLITK)   // 3072 per block
#define NT (KHALF / BK)       // 48 K-steps per block

// LDS: A 256 rows x 128 B = 32 KB ; B 192 rows x 128 B = 24 KB ; dbuf = 112 KB
#define ABYTES (BM * 128)
#define BBYTES (BN * 128)
#define BUFBYTES (ABYTES + BBYTES)

typedef __attribute__((ext_vector_type(8))) __bf16 bf16x8;
typedef __attribute__((ext_vector_type(4))) float f32x4;

// LDS row = 64 bf16 = 128 B. 16B-block swizzle (3-bit, measured 0 conflicts
// in rounds 2-4): blk = (k>>3) ^ (row&7) ^ ((row>>2)&7)
__device__ __forceinline__ char* lds_addr(char* base, int row, int k) {
  const int blk = ((k >> 3) ^ (row & 7) ^ ((row >> 2) & 7)) & 7;
  return base + row * 128 + (blk << 4) + ((k & 7) << 1);
}

// Non-draining barrier: drain LDS ops only; global loads stay in flight
// (__syncthreads would emit vmcnt(0) and serialize the pipeline).
#define BAR()                                              \
  do {                                                     \
    asm volatile("s_waitcnt lgkmcnt(0)" ::: "memory");     \
    __builtin_amdgcn_sched_barrier(0);                     \
    __builtin_amdgcn_s_barrier();                          \
    __builtin_amdgcn_sched_barrier(0);                     \
  } while (0)

// out[b,d] = sum_l bias[l,d]  (also clears the 0xAA poison deterministically)
__global__ __launch_bounds__(256) void bias_init_kernel(
    const float* __restrict__ bias, const int* __restrict__ lidx,
    float* __restrict__ out) {
  int n = lidx[0] + 1;
  int i = blockIdx.x * 256 + threadIdx.x;
  if (i >= NB * ND) return;
  int d = i % ND;
  float s = 0.f;
  for (int l = 0; l < n; ++l) s += bias[l * ND + d];
  out[i] = s;
}

__global__ __launch_bounds__(512, 2) void gemm_kernel(
    const float* __restrict__ acts, const float* __restrict__ W,
    const int* __restrict__ lidx, float* __restrict__ out, int nwg) {
  extern __shared__ char cbuf[];  // 2 * BUFBYTES

  // XCD-aware bijective swizzle (nwg = 768, 768%8==0): consecutive ids share
  // the same (by,l,ks) W panel-half (m fastest) -> panel stays in one XCD L2.
  const int chunk = nwg >> 3;  // 96
  const int swz = (blockIdx.x & 7) * chunk + (blockIdx.x >> 3);
  // id = m + 8*(ks + 2*(by + 4*l))
  const int m = swz & 7;
  int rem = swz >> 3;
  const int ks = rem & 1; rem >>= 1;
  const int by = rem & 3; rem >>= 2;
  const int l = rem;
  if (l > lidx[0]) return;  // uniform exit before any barrier

  const int brow = m * BM;
  const int ncol = by * BN;
  const int k0 = ks * KHALF;

  const int tid = threadIdx.x;
  const int lane = tid & 63;
  const int wid = tid >> 6;          // 8 waves: 4M x 2N
  const int wrow = (wid >> 1) * 64;  // 0,64,128,192
  const int wcol = (wid & 1) * 96;   // 0,96

  f32x4 acc[4][6];
#pragma unroll
  for (int i = 0; i < 4; ++i)
#pragma unroll
    for (int j = 0; j < 6; ++j) acc[i][j] = (f32x4){0.f, 0.f, 0.f, 0.f};

  // A staging: thread -> (row = tid>>3 (+64 per pass p<4), 8 consecutive k)
  const int s_arow = tid >> 3;        // 0..63
  const int s_ak = (tid & 7) * 8;     // 0..56
  // B staging: threads 0..383 (waves 0-5, wave-uniform): 4 d x 8 k each
  const bool bstage = tid < 384;
  const int s_bd = (tid % 48) * 4;    // 0..188
  const int s_bk = (tid / 48) * 8;    // 0..56 (tid<384)

  const float* Aptr =
      acts + (size_t)l * NB * NF + (size_t)(brow + s_arow) * NF + k0 + s_ak;
  const float* Bptr =
      W + (size_t)l * NF * ND + (size_t)(k0 + s_bk) * ND + (ncol + s_bd);

  // single staging set: 16 float4 = 64 VGPRs
  float4 av[4][2];  // A: 4 row-passes x 8 k
  float4 bv[8];     // B: 8 k-rows x 4 d

  auto LOADS = [&](int kb) {
#pragma unroll
    for (int p = 0; p < 4; ++p) {
      av[p][0] = *(const float4*)(Aptr + (size_t)(64 * p) * NF + kb);
      av[p][1] = *(const float4*)(Aptr + (size_t)(64 * p) * NF + kb + 4);
    }
    if (bstage) {
#pragma unroll
      for (int j = 0; j < 8; ++j)
        bv[j] = *(const float4*)(Bptr + (size_t)(kb + j) * ND);
    }
  };

  auto STORE = [&](int buf) {
    char* cA_ = cbuf + (size_t)buf * BUFBYTES;
    char* cB_ = cA_ + ABYTES;
#pragma unroll
    for (int p = 0; p < 4; ++p) {
      bf16x8 h;
      h[0] = (__bf16)av[p][0].x; h[1] = (__bf16)av[p][0].y;
      h[2] = (__bf16)av[p][0].z; h[3] = (__bf16)av[p][0].w;
      h[4] = (__bf16)av[p][1].x; h[5] = (__bf16)av[p][1].y;
      h[6] = (__bf16)av[p][1].z; h[7] = (__bf16)av[p][1].w;
      *(bf16x8*)lds_addr(cA_, s_arow + 64 * p, s_ak) = h;
    }
    if (bstage) {
#pragma unroll
      for (int dd = 0; dd < 4; ++dd) {
        bf16x8 h;
#pragma unroll
        for (int j = 0; j < 8; ++j) h[j] = (__bf16)bv[j][dd];
        *(bf16x8*)lds_addr(cB_, s_bd + dd, s_bk) = h;
      }
    }
  };

  auto KSTEP = [&](int buf, int s) {
    char* cA_ = cbuf + (size_t)buf * BUFBYTES;
    char* cB_ = cA_ + ABYTES;
    const int kk = s * 32 + (lane >> 4) * 8;
    bf16x8 aF[4], bF[6];
#pragma unroll
    for (int mi = 0; mi < 4; ++mi)
      aF[mi] = *(const bf16x8*)lds_addr(cA_, wrow + mi * 16 + (lane & 15), kk);
#pragma unroll
    for (int ni = 0; ni < 6; ++ni)
      bF[ni] = *(const bf16x8*)lds_addr(cB_, wcol + ni * 16 + (lane & 15), kk);
#pragma unroll
    for (int mi = 0; mi < 4; ++mi)
#pragma unroll
      for (int ni = 0; ni < 6; ++ni)
        acc[mi][ni] = __builtin_amdgcn_mfma_f32_16x16x32_bf16(
            aF[mi], bF[ni], acc[mi][ni], 0, 0, 0);
  };

  // ---- pipeline prologue ----
  LOADS(0);
  STORE(0);            // waits its own loads (startup only)
  LOADS(BK);           // slab 1 in flight across the whole first K-step

  // ---- main loop: one non-draining barrier per K-step, LDS double-buffer ---
  // BAR at top of iter t guarantees buf[t&1] fully written (STORE in t-1) and
  // buf[t^1] fully read (KSTEPs in t-1) via lgkmcnt(0); vmcnt stays in flight.
  // STORE placed AFTER both KSTEPs: load-issue -> consume distance ~= one full
  // MFMA phase (~2k cycles) which covers L2/HBM latency.
  for (int t = 0; t < NT; ++t) {
    BAR();
    const int cur = t & 1;
    KSTEP(cur, 0);
    KSTEP(cur, 1);
    if (t + 1 < NT) STORE(cur ^ 1);        // hw vmcnt wait via reg deps
    if (t + 2 < NT) LOADS((t + 2) * BK);   // consumed next iteration
  }

  // ---- epilogue: atomic accumulate (24 blocks collide per output: 12L x 2K) -
  // C/D layout (m89-verified): col = lane&15, row = (lane>>4)*4 + j
  const int orow = brow + wrow + ((lane >> 4) << 2);
  const int ocol = ncol + wcol + (lane & 15);
#pragma unroll
  for (int mi = 0; mi < 4; ++mi)
#pragma unroll
    for (int ni = 0; ni < 6; ++ni)
#pragma unroll
      for (int j = 0; j < 4; ++j)
        atomicAdd(out + (size_t)(orow + mi * 16 + j) * ND + (ocol + ni * 16),
                  acc[mi][ni][j]);
}

extern "C" void kernel_launch(void* const* d_in, const int* in_sizes, int n_in,
                              void* d_out, int out_size, void* d_ws, size_t ws_size,
                              hipStream_t stream) {
  const float* acts = (const float*)d_in[0];
  const float* W    = (const float*)d_in[1];
  const float* bias = (const float*)d_in[2];
  const int*   lidx = (const int*)d_in[3];
  float* out = (float*)d_out;

  const int L = in_sizes[0] / (NB * NF);                 // 12
  const int nwg = (NB / BM) * SPLITK * (ND / BN) * L;    // 768

  // 112 KB dynamic LDS (> 64 KB static limit). Unconditional + deterministic.
  hipFuncSetAttribute((const void*)gemm_kernel,
                      hipFuncAttributeMaxDynamicSharedMemorySize,
                      2 * BUFBYTES);

  bias_init_kernel<<<dim3((NB * ND + 255) / 256), 256, 0, stream>>>(bias, lidx, out);
  gemm_kernel<<<dim3(nwg), 512, 2 * BUFBYTES, stream>>>(acts, W, lidx, out, nwg);
}

// Round 7
// 538.868 us; speedup vs baseline: 1.1360x; 1.0686x over previous
//
#include <hip/hip_runtime.h>
#include <hip/hip_bf16.h>

#define NB 2048
#define NF 6144
#define ND 768
#define BK 64
#define NT (NF / BK)  // 96 K-steps per layer

typedef __attribute__((ext_vector_type(8))) __bf16 bf16x8;
typedef __attribute__((ext_vector_type(4))) float f32x4;

// LDS row = 64 bf16 = 128 B. 16B-block swizzle (3-bit, measured 0 conflicts
// rounds 2-4): blk = (k>>3) ^ (row&7) ^ ((row>>2)&7)
__device__ __forceinline__ char* lds_addr(char* base, int row, int k) {
  const int blk = ((k >> 3) ^ (row & 7) ^ ((row >> 2) & 7)) & 7;
  return base + row * 128 + (blk << 4) + ((k & 7) << 1);
}

// Non-draining barrier: drain LDS ops only; global loads stay in flight
// (__syncthreads would emit vmcnt(0) and serialize the pipeline).
#define BAR()                                              \
  do {                                                     \
    asm volatile("s_waitcnt lgkmcnt(0)" ::: "memory");     \
    __builtin_amdgcn_sched_barrier(0);                     \
    __builtin_amdgcn_s_barrier();                          \
    __builtin_amdgcn_sched_barrier(0);                     \
  } while (0)

// out[b,d] = sum_l bias[l,d]  (also clears the 0xAA poison deterministically)
__global__ __launch_bounds__(256) void bias_init_kernel(
    const float* __restrict__ bias, const int* __restrict__ lidx,
    float* __restrict__ out) {
  int n = lidx[0] + 1;
  int i = blockIdx.x * 256 + threadIdx.x;
  if (i >= NB * ND) return;
  int d = i % ND;
  float s = 0.f;
  for (int l = 0; l < n; ++l) s += bias[l * ND + d];
  out[i] = s;
}

// 128x128 tile, BK=64, SINGLE-buffer LDS (32 KB -> 3 blocks/CU), two
// lgkm-only barriers per K-step. A-slab register-prefetched one full
// iteration ahead; B loaded just-in-time in the store phase (reg budget:
// 3 waves/SIMD caps at 170 regs).
__global__ __launch_bounds__(256, 3) void gemm_kernel(
    const float* __restrict__ acts, const float* __restrict__ W,
    const int* __restrict__ lidx, float* __restrict__ out, int nwg) {
  // XCD-aware bijective swizzle (nwg=1152, %8==0): consecutive swz share the
  // same W panel (m fastest) -> panel stays hot in one XCD's L2.
  const int chunk = nwg >> 3;  // 144
  const int swz = (blockIdx.x & 7) * chunk + (blockIdx.x >> 3);
  const int m = swz & 15;       // id = m + 16*(by + 6*l)
  const int rem = swz >> 4;
  const int by = rem % 6;
  const int l = rem / 6;
  if (l > lidx[0]) return;  // uniform exit before any barrier

  const int brow = m * 128;
  const int ncol = by * 128;

  __shared__ char cA[16384];  // 128 rows(b) x 64 bf16(k), swizzled
  __shared__ char cB[16384];  // 128 rows(d) x 64 bf16(k), swizzled

  const int tid = threadIdx.x;
  const int lane = tid & 63;
  const int wid = tid >> 6;
  const int wrow = (wid >> 1) * 64;
  const int wcol = (wid & 1) * 64;

  f32x4 acc[4][4];
#pragma unroll
  for (int i = 0; i < 4; ++i)
#pragma unroll
    for (int j = 0; j < 4; ++j) acc[i][j] = (f32x4){0.f, 0.f, 0.f, 0.f};

  // A staging: thread -> (row = tid>>3 (+32 per pass), 8 consecutive k)
  const int s_arow = tid >> 3;
  const int s_ak = (tid & 7) * 8;
  // B staging: thread -> (4 consecutive d, 8 consecutive k)
  const int s_bd = (tid & 31) * 4;
  const int s_bk = (tid >> 5) * 8;

  const float* Aptr =
      acts + (size_t)l * NB * NF + (size_t)(brow + s_arow) * NF + s_ak;
  const float* Bptr =
      W + (size_t)l * NF * ND + (size_t)s_bk * ND + (ncol + s_bd);

  float4 av[4][2];  // A slab, prefetched one iteration ahead (32 VGPR)

  auto ALOADS = [&](int kb) {
#pragma unroll
    for (int p = 0; p < 4; ++p) {
      av[p][0] = *(const float4*)(Aptr + (size_t)(32 * p) * NF + kb);
      av[p][1] = *(const float4*)(Aptr + (size_t)(32 * p) * NF + kb + 4);
    }
  };

  // Store phase: issue B loads first (head start over the A cvt+write), then
  // A store (vmcnt-waits the 1-iter-old A loads), then B cvt+store.
  auto STORE = [&](int kb) {
    float4 bv[8];  // transient: live only inside the store phase
#pragma unroll
    for (int j = 0; j < 8; ++j)
      bv[j] = *(const float4*)(Bptr + (size_t)(kb + j) * ND);
#pragma unroll
    for (int p = 0; p < 4; ++p) {
      bf16x8 h;
      h[0] = (__bf16)av[p][0].x; h[1] = (__bf16)av[p][0].y;
      h[2] = (__bf16)av[p][0].z; h[3] = (__bf16)av[p][0].w;
      h[4] = (__bf16)av[p][1].x; h[5] = (__bf16)av[p][1].y;
      h[6] = (__bf16)av[p][1].z; h[7] = (__bf16)av[p][1].w;
      *(bf16x8*)lds_addr(cA, s_arow + 32 * p, s_ak) = h;
    }
#pragma unroll
    for (int dd = 0; dd < 4; ++dd) {
      bf16x8 h;
#pragma unroll
      for (int j = 0; j < 8; ++j) h[j] = (__bf16)bv[j][dd];
      *(bf16x8*)lds_addr(cB, s_bd + dd, s_bk) = h;
    }
  };

  auto KSTEP = [&](int s) {
    const int kk = s * 32 + (lane >> 4) * 8;
    bf16x8 aF[4], bF[4];
#pragma unroll
    for (int mi = 0; mi < 4; ++mi)
      aF[mi] = *(const bf16x8*)lds_addr(cA, wrow + mi * 16 + (lane & 15), kk);
#pragma unroll
    for (int ni = 0; ni < 4; ++ni)
      bF[ni] = *(const bf16x8*)lds_addr(cB, wcol + ni * 16 + (lane & 15), kk);
#pragma unroll
    for (int mi = 0; mi < 4; ++mi)
#pragma unroll
      for (int ni = 0; ni < 4; ++ni)
        acc[mi][ni] = __builtin_amdgcn_mfma_f32_16x16x32_bf16(
            aF[mi], bF[ni], acc[mi][ni], 0, 0, 0);
  };

  // ---- prologue: slab 0 into LDS; slab 1 A-loads in flight ----
  ALOADS(0);
  STORE(0);      // waits its own A loads (startup only)
  ALOADS(BK);    // A slab 1 in flight across iter 0's compute

  // ---- main loop: single LDS buffer, 2 lgkm-only barriers per K-step ----
  // BAR#1 = RAW (STORE of t visible before KSTEP of t);
  // BAR#2 = WAR (KSTEP reads of t done before STORE of t+1 overwrites).
  // Global A loads stay in flight across both barriers (1-iter depth);
  // B's JIT latency is covered by the other 2 resident blocks.
  for (int t = 0; t < NT; ++t) {
    BAR();
    KSTEP(0);
    KSTEP(1);
    BAR();
    if (t + 1 < NT) STORE((t + 1) * BK);
    if (t + 2 < NT) ALOADS((t + 2) * BK);
  }

  // ---- epilogue: atomic accumulate (12 layer-blocks collide per output) ----
  // C/D layout (m89-verified): col = lane&15, row = (lane>>4)*4 + j
  const int orow = brow + wrow + ((lane >> 4) << 2);
  const int ocol = ncol + wcol + (lane & 15);
#pragma unroll
  for (int mi = 0; mi < 4; ++mi)
#pragma unroll
    for (int ni = 0; ni < 4; ++ni)
#pragma unroll
      for (int j = 0; j < 4; ++j)
        atomicAdd(out + (size_t)(orow + mi * 16 + j) * ND + (ocol + ni * 16),
                  acc[mi][ni][j]);
}

extern "C" void kernel_launch(void* const* d_in, const int* in_sizes, int n_in,
                              void* d_out, int out_size, void* d_ws, size_t ws_size,
                              hipStream_t stream) {
  const float* acts = (const float*)d_in[0];
  const float* W    = (const float*)d_in[1];
  const float* bias = (const float*)d_in[2];
  const int*   lidx = (const int*)d_in[3];
  float* out = (float*)d_out;

  const int L = in_sizes[0] / (NB * NF);        // 12
  const int nwg = (NB / 128) * (ND / 128) * L;  // 1152

  bias_init_kernel<<<dim3((NB * ND + 255) / 256), 256, 0, stream>>>(bias, lidx, out);
  gemm_kernel<<<dim3(nwg), 256, 0, stream>>>(acts, W, lidx, out, nwg);
}

// Round 8
// 475.322 us; speedup vs baseline: 1.2878x; 1.1337x over previous
//
#include <hip/hip_runtime.h>
#include <hip/hip_bf16.h>

#define NB 2048
#define NF 6144
#define ND 768
#define BM 256
#define BN 192
#define BK 64
#define SPLITK 2
#define KCH (NF / SPLITK)  // 3072 per block
#define NTIL (KCH / BK)    // 48 K-tiles per block

// LDS: A 256 rows x 128 B = 32 KB; B 192 rows x 128 B = 24 KB; dbuf = 112 KB
#define ABYTES (BM * 128)
#define BBYTES (BN * 128)
#define BUFBYTES (ABYTES + BBYTES)

typedef __attribute__((ext_vector_type(8))) __bf16 bf16x8;
typedef __attribute__((ext_vector_type(4))) float f32x4;

// LDS row = 64 bf16 = 128 B. 16B-block swizzle (3-bit, measured 0 conflicts
// rounds 2-4,6,7): blk = (k>>3) ^ (row&7) ^ ((row>>2)&7)
__device__ __forceinline__ char* lds_addr(char* base, int row, int k) {
  const int blk = ((k >> 3) ^ (row & 7) ^ ((row >> 2) & 7)) & 7;
  return base + row * 128 + (blk << 4) + ((k & 7) << 1);
}

// Non-draining barrier: drain LDS ops only; global loads stay in flight.
#define BAR()                                              \
  do {                                                     \
    asm volatile("s_waitcnt lgkmcnt(0)" ::: "memory");     \
    __builtin_amdgcn_sched_barrier(0);                     \
    __builtin_amdgcn_s_barrier();                          \
    __builtin_amdgcn_sched_barrier(0);                     \
  } while (0)

// out[b,d] = sum_l bias[l,d]  (also clears the 0xAA poison deterministically)
__global__ __launch_bounds__(256) void bias_init_kernel(
    const float* __restrict__ bias, const int* __restrict__ lidx,
    float* __restrict__ out) {
  int n = lidx[0] + 1;
  int i = blockIdx.x * 256 + threadIdx.x;
  if (i >= NB * ND) return;
  int d = i % ND;
  float s = 0.f;
  for (int l = 0; l < n; ++l) s += bias[l * ND + d];
  out[i] = s;
}

// 256x192 tile, 8 waves (4m x 2n, wave = 64x96), BK=64, split-K x2.
// Per K-tile: BAR -> issue all staging loads -> 3 phase-interleaved MFMA
// clusters (setprio-wrapped) -> cvt+ds_write to the other LDS buffer.
// Loads are consumed ~3 MFMA phases (~1900 cyc) after issue: latency is
// covered INSIDE the iteration, no cross-barrier register live ranges.
__global__ __launch_bounds__(512, 2) void gemm_kernel(
    const float* __restrict__ acts, const float* __restrict__ W,
    const int* __restrict__ lidx, float* __restrict__ out, int nwg) {
  extern __shared__ char cbuf[];  // 2 * BUFBYTES

  // Decode with `by` FASTEST so the 4 blocks sharing an A-slab are swz-
  // consecutive; XCD swizzle then pins them to one XCD -> A-slab fetched from
  // HBM once, W panel (2.25 MB) stays hot in that XCD's L2/L3.
  const int chunk = nwg >> 3;  // 96
  const int swz = (blockIdx.x & 7) * chunk + (blockIdx.x >> 3);
  const int by = swz & 3;            // id = by + 4*(m + 8*(ks + 2*l))
  int rem = swz >> 2;
  const int m = rem & 7; rem >>= 3;
  const int ks = rem & 1; rem >>= 1;
  const int l = rem;
  if (l > lidx[0]) return;  // uniform exit before any barrier

  const int brow = m * BM;
  const int ncol = by * BN;
  const int k0 = ks * KCH;

  const int tid = threadIdx.x;
  const int lane = tid & 63;
  const int wid = tid >> 6;          // 8 waves: 4m x 2n
  const int wrow = (wid >> 1) * 64;  // 0,64,128,192
  const int wcol = (wid & 1) * 96;   // 0,96

  f32x4 acc[4][6];
#pragma unroll
  for (int i = 0; i < 4; ++i)
#pragma unroll
    for (int j = 0; j < 6; ++j) acc[i][j] = (f32x4){0.f, 0.f, 0.f, 0.f};

  // A staging: thread -> (row = tid>>3 (+64 per pass p<4), 8 consecutive k)
  const int s_arow = tid >> 3;        // 0..63
  const int s_ak = (tid & 7) * 8;     // 0..56
  // B staging: threads 0..383: (4 consecutive d, 8 consecutive k)
  const bool bstage = tid < 384;
  const int s_bd = (tid % 48) * 4;    // 0..188
  const int s_bk = (tid / 48) * 8;    // 0..56

  const float* Aptr =
      acts + (size_t)l * NB * NF + (size_t)(brow + s_arow) * NF + k0 + s_ak;
  const float* Bptr =
      W + (size_t)l * NF * ND + (size_t)(k0 + s_bk) * ND + (ncol + s_bd);

  float4 av[4][2];  // A: 4 row-passes x 8 k (32 VGPR)
  float4 bv[8];     // B: 8 k-rows x 4 d   (32 VGPR, waves 0-5)

  auto LOADS = [&](int kb) {
#pragma unroll
    for (int p = 0; p < 4; ++p) {
      av[p][0] = *(const float4*)(Aptr + (size_t)(64 * p) * NF + kb);
      av[p][1] = *(const float4*)(Aptr + (size_t)(64 * p) * NF + kb + 4);
    }
    if (bstage) {
#pragma unroll
      for (int j = 0; j < 8; ++j)
        bv[j] = *(const float4*)(Bptr + (size_t)(kb + j) * ND);
    }
  };

  auto STORE = [&](char* cA_, char* cB_) {
#pragma unroll
    for (int p = 0; p < 4; ++p) {
      bf16x8 h;
      h[0] = (__bf16)av[p][0].x; h[1] = (__bf16)av[p][0].y;
      h[2] = (__bf16)av[p][0].z; h[3] = (__bf16)av[p][0].w;
      h[4] = (__bf16)av[p][1].x; h[5] = (__bf16)av[p][1].y;
      h[6] = (__bf16)av[p][1].z; h[7] = (__bf16)av[p][1].w;
      *(bf16x8*)lds_addr(cA_, s_arow + 64 * p, s_ak) = h;
    }
    if (bstage) {
#pragma unroll
      for (int dd = 0; dd < 4; ++dd) {
        bf16x8 h;
#pragma unroll
        for (int j = 0; j < 8; ++j) h[j] = (__bf16)bv[j][dd];
        *(bf16x8*)lds_addr(cB_, s_bd + dd, s_bk) = h;
      }
    }
  };

  // ---- prologue: tile 0 into buf0 (self-waiting, once) ----
  LOADS(0);
  STORE(cbuf, cbuf + ABYTES);

  for (int t = 0; t < NTIL; ++t) {
    BAR();  // buf[t&1] fully written & buf[(t&1)^1] fully read (lgkm drain)
    const int cur = t & 1;
    char* rA = cbuf + (size_t)cur * BUFBYTES;
    char* rB = rA + ABYTES;
    char* wA = cbuf + (size_t)(cur ^ 1) * BUFBYTES;
    char* wB = wA + ABYTES;

    if (t + 1 < NTIL) LOADS((t + 1) * BK);  // consumed after 3 MFMA phases
    __builtin_amdgcn_sched_barrier(0);

    // A fragments for all 3 phases (read once, 32 VGPR)
    bf16x8 aF[4][2];
#pragma unroll
    for (int mi = 0; mi < 4; ++mi)
#pragma unroll
      for (int s = 0; s < 2; ++s)
        aF[mi][s] = *(const bf16x8*)lds_addr(
            rA, wrow + mi * 16 + (lane & 15), s * 32 + (lane >> 4) * 8);

    // 3 phases: each reads one B n-pair, then a 16-MFMA cluster
#pragma unroll
    for (int p = 0; p < 3; ++p) {
      bf16x8 bF[2][2];
#pragma unroll
      for (int ni = 0; ni < 2; ++ni)
#pragma unroll
        for (int s = 0; s < 2; ++s)
          bF[ni][s] = *(const bf16x8*)lds_addr(
              rB, wcol + (2 * p + ni) * 16 + (lane & 15),
              s * 32 + (lane >> 4) * 8);
      __builtin_amdgcn_s_setprio(1);
#pragma unroll
      for (int s = 0; s < 2; ++s)
#pragma unroll
        for (int mi = 0; mi < 4; ++mi)
#pragma unroll
          for (int ni = 0; ni < 2; ++ni)
            acc[mi][2 * p + ni] = __builtin_amdgcn_mfma_f32_16x16x32_bf16(
                aF[mi][s], bF[ni][s], acc[mi][2 * p + ni], 0, 0, 0);
      __builtin_amdgcn_s_setprio(0);
      __builtin_amdgcn_sched_barrier(0);
    }

    // cvt+write next tile (reg-dep vmcnt wait; loads are ~3 phases old)
    if (t + 1 < NTIL) STORE(wA, wB);
  }

  // ---- epilogue: atomic accumulate (24 blocks collide: 12L x 2K) ----
  // C/D layout (m89-verified): col = lane&15, row = (lane>>4)*4 + j
  const int orow = brow + wrow + ((lane >> 4) << 2);
  const int ocol = ncol + wcol + (lane & 15);
#pragma unroll
  for (int mi = 0; mi < 4; ++mi)
#pragma unroll
    for (int ni = 0; ni < 6; ++ni)
#pragma unroll
      for (int j = 0; j < 4; ++j)
        atomicAdd(out + (size_t)(orow + mi * 16 + j) * ND + (ocol + ni * 16),
                  acc[mi][ni][j]);
}

extern "C" void kernel_launch(void* const* d_in, const int* in_sizes, int n_in,
                              void* d_out, int out_size, void* d_ws, size_t ws_size,
                              hipStream_t stream) {
  const float* acts = (const float*)d_in[0];
  const float* W    = (const float*)d_in[1];
  const float* bias = (const float*)d_in[2];
  const int*   lidx = (const int*)d_in[3];
  float* out = (float*)d_out;

  const int L = in_sizes[0] / (NB * NF);              // 12
  const int nwg = (ND / BN) * (NB / BM) * SPLITK * L; // 768 = 3 x 256 CUs

  hipFuncSetAttribute((const void*)gemm_kernel,
                      hipFuncAttributeMaxDynamicSharedMemorySize,
                      2 * BUFBYTES);

  bias_init_kernel<<<dim3((NB * ND + 255) / 256), 256, 0, stream>>>(bias, lidx, out);
  gemm_kernel<<<dim3(nwg), 512, 2 * BUFBYTES, stream>>>(acts, W, lidx, out, nwg);
}